// Round 6
// baseline (1439.226 us; speedup 1.0000x reference)
//
#include <hip/hip_runtime.h>
#include <math.h>

// ---------------------------------------------------------------------------
// tNN over DCT domain: 4 layers of  IDCT28 * blockdiag_k(What_k) * DCT28
// with bias+ReLU in spatial domain between layers.
//
//  - prep_kernel (128 blocks, grid-stride): folds DCT into weights
//    (What = C @ W), builds packed even/odd DCT tables + transposed biases.
//  - tnn_kernel: 1 block = 16 columns, 448 threads = 28 (row) x 16 (col).
//    Whole 28x28x16 activation tile in ONE LDS buffer; stages in-place.
//    Even/odd butterfly DCT (420 ops vs 784); IDCT+bias+ReLU+next-DCT fused
//    in registers. DCT tables -> wave-uniform s_loads; What -> float4 loads.
//  - __launch_bounds__(448, 2): R5 post-mortem — (448,4) made the compiler
//    cap at 64 VGPR -> 56-float working set spilled to scratch (WRITE_SIZE
//    308MB vs 73MB true output, VALUBusy 54%). (448,2) gives >=128 VGPR cap:
//    no spill, >=2 blocks/CU (LDS still allows 3).
//  - XCD-chunked bijective blockIdx swizzle for x/out L2 line locality.
// ---------------------------------------------------------------------------

#define NT 16
#define ROWSTRIDE (28 * NT + 8) // 456 words; %32==8 -> all accesses <=2-way (free)

// workspace layout (float offsets)
#define OFF_CP 0                    // [28][16] C[k][i] i<14 (pad 2)
#define OFF_CTE 448                 // [14][16] CtE[i][j] = C[2j][i]
#define OFF_CTO 672                 // [14][16] CtO[i][j] = C[2j+1][i]
#define OFF_WH1 896
#define OFF_WH2 (OFF_WH1 + 21952)
#define OFF_WH3 (OFF_WH2 + 21952)
#define OFF_WH4 (OFF_WH3 + 21952)
#define OFF_BT1 (OFF_WH4 + 7840)
#define OFF_BT2 (OFF_BT1 + 784)
#define OFF_BT3 (OFF_BT2 + 784)
#define OFF_BT4 (OFF_BT3 + 784)

__global__ void prep_kernel(const float* __restrict__ W1, const float* __restrict__ B1,
                            const float* __restrict__ W2, const float* __restrict__ B2,
                            const float* __restrict__ W3, const float* __restrict__ B3,
                            const float* __restrict__ W4, const float* __restrict__ B4,
                            float* __restrict__ ws) {
  __shared__ float Cs[784]; // per-block copy of the DCT matrix C[k][i]
  const int tid = threadIdx.x;
  for (int idx = tid; idx < 784; idx += blockDim.x) {
    int k = idx / 28, i = idx - k * 28;
    double ang = (3.14159265358979323846 * (double)((2 * i + 1) * k)) / 56.0;
    double sc = (k == 0) ? sqrt(1.0 / 28.0) : sqrt(2.0 / 28.0);
    Cs[idx] = (float)(cos(ang) * sc);
  }
  __syncthreads();

  if (blockIdx.x == 0) { // tiny tables: one block handles them
    for (int idx = tid; idx < 448; idx += blockDim.x) {
      int k = idx >> 4, i = idx & 15;
      ws[OFF_CP + idx] = (i < 14) ? Cs[k * 28 + i] : 0.f;
    }
    for (int idx = tid; idx < 224; idx += blockDim.x) {
      int i = idx >> 4, j = idx & 15;
      ws[OFF_CTE + idx] = (j < 14) ? Cs[(2 * j) * 28 + i] : 0.f;
      ws[OFF_CTO + idx] = (j < 14) ? Cs[(2 * j + 1) * 28 + i] : 0.f;
    }
    for (int idx = tid; idx < 784; idx += blockDim.x) {
      int a = idx / 28, l = idx - a * 28;
      ws[OFF_BT1 + idx] = B1[l * 28 + a];
      ws[OFF_BT2 + idx] = B2[l * 28 + a];
      ws[OFF_BT3 + idx] = B3[l * 28 + a];
    }
    for (int idx = tid; idx < 280; idx += blockDim.x) {
      int a = idx / 28, l = idx - a * 28;
      ws[OFF_BT4 + idx] = B4[l * 10 + a];
    }
  }

  const int gbase = blockIdx.x * blockDim.x + tid;
  const int gstride = gridDim.x * blockDim.x;

#define FOLD28(W, OFFW)                                                      \
  for (int idx = gbase; idx < 21952; idx += gstride) {                       \
    int k = idx / 784, r = idx - k * 784;                                    \
    const float* cr = Cs + k * 28;                                           \
    float s = 0.f;                                                           \
    _Pragma("unroll") for (int l = 0; l < 28; ++l)                           \
        s = fmaf(cr[l], W[l * 784 + r], s);                                  \
    ws[OFFW + idx] = s;                                                      \
  }
  FOLD28(W1, OFF_WH1)
  FOLD28(W2, OFF_WH2)
  FOLD28(W3, OFF_WH3)
#undef FOLD28
  for (int idx = gbase; idx < 7840; idx += gstride) { // layer 4: a-dim = 10
    int k = idx / 280, r = idx - k * 280;
    const float* cr = Cs + k * 28;
    float s = 0.f;
#pragma unroll
    for (int l = 0; l < 28; ++l) s = fmaf(cr[l], W4[l * 280 + r], s);
    ws[OFF_WH4 + idx] = s;
  }
}

// 14-term dot, contiguous h (uniform w base -> s_loads)
__device__ __forceinline__ float dot14(const float* __restrict__ w, const float* h) {
  float s0 = 0.f, s1 = 0.f, s2 = 0.f, s3 = 0.f;
#pragma unroll
  for (int j = 0; j < 12; j += 4) {
    s0 = fmaf(w[j + 0], h[j + 0], s0);
    s1 = fmaf(w[j + 1], h[j + 1], s1);
    s2 = fmaf(w[j + 2], h[j + 2], s2);
    s3 = fmaf(w[j + 3], h[j + 3], s3);
  }
  s0 = fmaf(w[12], h[12], s0);
  s1 = fmaf(w[13], h[13], s1);
  return (s0 + s1) + (s2 + s3);
}

// 14-term dot over h[2j+OFF] (even/odd halves of a 28-vector)
template <int OFF>
__device__ __forceinline__ float dot14_str2(const float* __restrict__ w, const float* h) {
  float s0 = 0.f, s1 = 0.f, s2 = 0.f, s3 = 0.f;
#pragma unroll
  for (int j = 0; j < 12; j += 4) {
    s0 = fmaf(w[j + 0], h[2 * j + OFF + 0], s0);
    s1 = fmaf(w[j + 1], h[2 * j + OFF + 2], s1);
    s2 = fmaf(w[j + 2], h[2 * j + OFF + 4], s2);
    s3 = fmaf(w[j + 3], h[2 * j + OFF + 6], s3);
  }
  s0 = fmaf(w[12], h[24 + OFF], s0);
  s1 = fmaf(w[13], h[26 + OFF], s1);
  return (s0 + s1) + (s2 + s3);
}

// 28-term dot via 7 float4 vector loads (lane-varying base)
__device__ __forceinline__ float dotw4(const float4* __restrict__ w4, const float* h) {
  float s0 = 0.f, s1 = 0.f, s2 = 0.f, s3 = 0.f;
#pragma unroll
  for (int q = 0; q < 7; ++q) {
    float4 w = w4[q];
    s0 = fmaf(w.x, h[4 * q + 0], s0);
    s1 = fmaf(w.y, h[4 * q + 1], s1);
    s2 = fmaf(w.z, h[4 * q + 2], s2);
    s3 = fmaf(w.w, h[4 * q + 3], s3);
  }
  return (s0 + s1) + (s2 + s3);
}

__global__ __launch_bounds__(448, 2) void tnn_kernel(const float* __restrict__ x,
                                                     const float* __restrict__ ws,
                                                     float* __restrict__ out, int N) {
  __shared__ float lds[28 * ROWSTRIDE];
  const int tid = threadIdx.x;
  const int nt = tid & (NT - 1);
  const int row = tid >> 4; // 0..27

  // XCD-chunked bijective swizzle: consecutive data-blocks -> same XCD's L2,
  // so adjacent 64B halves of 128B x/out lines are reused, not re-fetched.
  const int nwg = gridDim.x;
  int bid = blockIdx.x;
  if ((nwg & 7) == 0) bid = (bid & 7) * (nwg >> 3) + (bid >> 3);

  const int nb = bid * NT + nt;
  const int nbm = (nb < N) ? nb : (N - 1); // clamp loads; stores masked
  const int col = row * NT + nt;           // this thread's LDS column offset

  const float* Cp = ws + OFF_CP;
  const float* CtE = ws + OFF_CTE;
  const float* CtO = ws + OFF_CTO;

  float h[28], u[14], v[14];

  // ---- Stage A1: DCT along tube of x[:, row, nb] (even/odd butterfly)
#pragma unroll
  for (int m = 0; m < 28; ++m) h[m] = x[(size_t)(m * 28 + row) * N + nbm];
#pragma unroll
  for (int i = 0; i < 14; ++i) {
    u[i] = h[i] + h[27 - i];
    v[i] = h[i] - h[27 - i];
  }
#pragma unroll
  for (int k = 0; k < 28; ++k) {
    const float* uv = (k & 1) ? v : u;
    lds[k * ROWSTRIDE + col] = dot14(Cp + k * 16, uv);
  }
  __syncthreads();

  // ---- layers 1..3
#pragma unroll 1
  for (int L = 0; L < 3; ++L) {
    const float* Wh = ws + (L == 0 ? OFF_WH1 : L == 1 ? OFF_WH2 : OFF_WH3);
    const float* bt = ws + (L == 0 ? OFF_BT1 : L == 1 ? OFF_BT2 : OFF_BT3) + row * 28;

    // Stage B: per-k matvec (row = k), in-place on own row
#pragma unroll
    for (int b = 0; b < 28; ++b) h[b] = lds[row * ROWSTRIDE + b * NT + nt];
    {
      const float4* wb = reinterpret_cast<const float4*>(Wh + row * 784);
#pragma unroll 2
      for (int a = 0; a < 28; ++a)
        lds[row * ROWSTRIDE + a * NT + nt] = dotw4(wb + a * 7, h);
    }
    __syncthreads();

    // Stage C+A fused (row = a): IDCT butterfly + bias + ReLU + fwd-DCT, in regs
#pragma unroll
    for (int k = 0; k < 28; ++k) h[k] = lds[k * ROWSTRIDE + col];
#pragma unroll
    for (int i = 0; i < 14; ++i) {
      float E = dot14_str2<0>(CtE + i * 16, h); // even-k partial
      float O = dot14_str2<1>(CtO + i * 16, h); // odd-k partial
      float yi = fmaxf(E + O + bt[i], 0.f);      // y[i]
      float yr = fmaxf(E - O + bt[27 - i], 0.f); // y[27-i]
      u[i] = yi + yr;
      v[i] = yi - yr;
    }
#pragma unroll
    for (int k = 0; k < 28; ++k) {
      const float* uv = (k & 1) ? v : u;
      lds[k * ROWSTRIDE + col] = dot14(Cp + k * 16, uv);
    }
    __syncthreads();
  }

  // ---- layer 4: Stage B4 (10 outputs per k-row)
#pragma unroll
  for (int b = 0; b < 28; ++b) h[b] = lds[row * ROWSTRIDE + b * NT + nt];
  {
    const float4* wb4 = reinterpret_cast<const float4*>(ws + OFF_WH4 + row * 280);
#pragma unroll
    for (int a = 0; a < 10; ++a)
      lds[row * ROWSTRIDE + a * NT + nt] = dotw4(wb4 + a * 7, h);
  }
  __syncthreads();

  // ---- Stage C4: IDCT butterfly + bias, store (rows 0..9 active)
  if (row < 10 && nb < N) {
#pragma unroll
    for (int k = 0; k < 28; ++k) h[k] = lds[k * ROWSTRIDE + col];
    const float* bt4 = ws + OFF_BT4 + row * 28;
#pragma unroll
    for (int i = 0; i < 14; ++i) {
      float E = dot14_str2<0>(CtE + i * 16, h);
      float O = dot14_str2<1>(CtO + i * 16, h);
      out[(size_t)(i * 10 + row) * N + nb] = E + O + bt4[i];
      out[(size_t)((27 - i) * 10 + row) * N + nb] = E - O + bt4[27 - i];
    }
  }
}

extern "C" void kernel_launch(void* const* d_in, const int* in_sizes, int n_in,
                              void* d_out, int out_size, void* d_ws, size_t ws_size,
                              hipStream_t stream) {
  const float* x = (const float*)d_in[0];
  const float* W1 = (const float*)d_in[1];
  const float* B1 = (const float*)d_in[2];
  const float* W2 = (const float*)d_in[3];
  const float* B2 = (const float*)d_in[4];
  const float* W3 = (const float*)d_in[5];
  const float* B3 = (const float*)d_in[6];
  const float* W4 = (const float*)d_in[7];
  const float* B4 = (const float*)d_in[8];
  float* ws = (float*)d_ws;

  const int N = in_sizes[0] / 784; // x is (28, 28, N)

  prep_kernel<<<128, 256, 0, stream>>>(W1, B1, W2, B2, W3, B3, W4, B4, ws);

  const int blocks = (N + NT - 1) / NT;
  tnn_kernel<<<blocks, 448, 0, stream>>>(x, ws, (float*)d_out, N);
}

// Round 9
// 1261.857 us; speedup vs baseline: 1.1406x; 1.1406x over previous
//
#include <hip/hip_runtime.h>
#include <math.h>

// ---------------------------------------------------------------------------
// tNN over DCT domain: 4 layers of  IDCT28 * blockdiag_k(What_k) * DCT28
// with bias+ReLU in spatial domain between layers.
//
//  R6 post-mortem: the fused IDCT+ReLU+DCT stage needed 56 live floats; the
//  allocator refuses >72 VGPR for 7-wave blocks under any launch_bounds and
//  spilled (R5: 235MB, R6: 58MB scratch writes; VALUBusy ~50%). Fix: split
//  the fusion with an LDS round-trip of the butterfly vector (u/v), capping
//  peak liveness at ~34 floats (~55 VGPR demand) -> no spill at the 64-VGPR
//  allocation that (448,4) empirically produces.
//
//  - prep_kernel: folds DCT into weights (What = C @ W), packed even/odd DCT
//    tables + transposed biases.
//  - tnn_kernel: 1 block = 16 columns, 448 threads = 28 (row) x 16 (col).
//    One 28x28x16 LDS tile, all stages in-place, 2 barriers/layer.
//    Stage B  (row=k):   h=own row; out[a] = What[k][a][.] . h     (float4 w)
//    Stage C' (col):     h=own col; E/O butterfly, +bias, ReLU, write u/v
//    Stage A' (col):     reload u/v, out[k] = C[k][.] . (k odd ? v : u)
//  - XCD-chunked bijective blockIdx swizzle for x/out L2 line locality.
// ---------------------------------------------------------------------------

#define NT 16
#define ROWSTRIDE (28 * NT + 8) // 456 words; %32==8 -> all accesses <=2-way (free)

// workspace layout (float offsets)
#define OFF_CP 0                    // [28][16] C[k][i] i<14 (pad 2)
#define OFF_CTE 448                 // [14][16] CtE[i][j] = C[2j][i]
#define OFF_CTO 672                 // [14][16] CtO[i][j] = C[2j+1][i]
#define OFF_WH1 896
#define OFF_WH2 (OFF_WH1 + 21952)
#define OFF_WH3 (OFF_WH2 + 21952)
#define OFF_WH4 (OFF_WH3 + 21952)
#define OFF_BT1 (OFF_WH4 + 7840)
#define OFF_BT2 (OFF_BT1 + 784)
#define OFF_BT3 (OFF_BT2 + 784)
#define OFF_BT4 (OFF_BT3 + 784)

__global__ void prep_kernel(const float* __restrict__ W1, const float* __restrict__ B1,
                            const float* __restrict__ W2, const float* __restrict__ B2,
                            const float* __restrict__ W3, const float* __restrict__ B3,
                            const float* __restrict__ W4, const float* __restrict__ B4,
                            float* __restrict__ ws) {
  __shared__ float Cs[784]; // per-block copy of the DCT matrix C[k][i]
  const int tid = threadIdx.x;
  for (int idx = tid; idx < 784; idx += blockDim.x) {
    int k = idx / 28, i = idx - k * 28;
    double ang = (3.14159265358979323846 * (double)((2 * i + 1) * k)) / 56.0;
    double sc = (k == 0) ? sqrt(1.0 / 28.0) : sqrt(2.0 / 28.0);
    Cs[idx] = (float)(cos(ang) * sc);
  }
  __syncthreads();

  if (blockIdx.x == 0) { // tiny tables: one block handles them
    for (int idx = tid; idx < 448; idx += blockDim.x) {
      int k = idx >> 4, i = idx & 15;
      ws[OFF_CP + idx] = (i < 14) ? Cs[k * 28 + i] : 0.f;
    }
    for (int idx = tid; idx < 224; idx += blockDim.x) {
      int i = idx >> 4, j = idx & 15;
      ws[OFF_CTE + idx] = (j < 14) ? Cs[(2 * j) * 28 + i] : 0.f;
      ws[OFF_CTO + idx] = (j < 14) ? Cs[(2 * j + 1) * 28 + i] : 0.f;
    }
    for (int idx = tid; idx < 784; idx += blockDim.x) {
      int a = idx / 28, l = idx - a * 28;
      ws[OFF_BT1 + idx] = B1[l * 28 + a];
      ws[OFF_BT2 + idx] = B2[l * 28 + a];
      ws[OFF_BT3 + idx] = B3[l * 28 + a];
    }
    for (int idx = tid; idx < 280; idx += blockDim.x) {
      int a = idx / 28, l = idx - a * 28;
      ws[OFF_BT4 + idx] = B4[l * 10 + a];
    }
  }

  const int gbase = blockIdx.x * blockDim.x + tid;
  const int gstride = gridDim.x * blockDim.x;

#define FOLD28(W, OFFW)                                                      \
  for (int idx = gbase; idx < 21952; idx += gstride) {                       \
    int k = idx / 784, r = idx - k * 784;                                    \
    const float* cr = Cs + k * 28;                                           \
    float s = 0.f;                                                           \
    _Pragma("unroll") for (int l = 0; l < 28; ++l)                           \
        s = fmaf(cr[l], W[l * 784 + r], s);                                  \
    ws[OFFW + idx] = s;                                                      \
  }
  FOLD28(W1, OFF_WH1)
  FOLD28(W2, OFF_WH2)
  FOLD28(W3, OFF_WH3)
#undef FOLD28
  for (int idx = gbase; idx < 7840; idx += gstride) { // layer 4: a-dim = 10
    int k = idx / 280, r = idx - k * 280;
    const float* cr = Cs + k * 28;
    float s = 0.f;
#pragma unroll
    for (int l = 0; l < 28; ++l) s = fmaf(cr[l], W4[l * 280 + r], s);
    ws[OFF_WH4 + idx] = s;
  }
}

// 14-term dot, contiguous h (uniform w base -> s_loads)
__device__ __forceinline__ float dot14(const float* __restrict__ w, const float* h) {
  float s0 = 0.f, s1 = 0.f, s2 = 0.f, s3 = 0.f;
#pragma unroll
  for (int j = 0; j < 12; j += 4) {
    s0 = fmaf(w[j + 0], h[j + 0], s0);
    s1 = fmaf(w[j + 1], h[j + 1], s1);
    s2 = fmaf(w[j + 2], h[j + 2], s2);
    s3 = fmaf(w[j + 3], h[j + 3], s3);
  }
  s0 = fmaf(w[12], h[12], s0);
  s1 = fmaf(w[13], h[13], s1);
  return (s0 + s1) + (s2 + s3);
}

// 14-term dot over h[2j+OFF] (even/odd halves of a 28-vector)
template <int OFF>
__device__ __forceinline__ float dot14_str2(const float* __restrict__ w, const float* h) {
  float s0 = 0.f, s1 = 0.f, s2 = 0.f, s3 = 0.f;
#pragma unroll
  for (int j = 0; j < 12; j += 4) {
    s0 = fmaf(w[j + 0], h[2 * j + OFF + 0], s0);
    s1 = fmaf(w[j + 1], h[2 * j + OFF + 2], s1);
    s2 = fmaf(w[j + 2], h[2 * j + OFF + 4], s2);
    s3 = fmaf(w[j + 3], h[2 * j + OFF + 6], s3);
  }
  s0 = fmaf(w[12], h[24 + OFF], s0);
  s1 = fmaf(w[13], h[26 + OFF], s1);
  return (s0 + s1) + (s2 + s3);
}

// 28-term dot via 7 float4 vector loads (lane-varying base)
__device__ __forceinline__ float dotw4(const float4* __restrict__ w4, const float* h) {
  float s0 = 0.f, s1 = 0.f, s2 = 0.f, s3 = 0.f;
#pragma unroll
  for (int q = 0; q < 7; ++q) {
    float4 w = w4[q];
    s0 = fmaf(w.x, h[4 * q + 0], s0);
    s1 = fmaf(w.y, h[4 * q + 1], s1);
    s2 = fmaf(w.z, h[4 * q + 2], s2);
    s3 = fmaf(w.w, h[4 * q + 3], s3);
  }
  return (s0 + s1) + (s2 + s3);
}

__global__ __launch_bounds__(448, 4) void tnn_kernel(const float* __restrict__ x,
                                                     const float* __restrict__ ws,
                                                     float* __restrict__ out, int N) {
  __shared__ float lds[28 * ROWSTRIDE];
  const int tid = threadIdx.x;
  const int nt = tid & (NT - 1);
  const int row = tid >> 4; // 0..27

  // XCD-chunked bijective swizzle: consecutive data-blocks -> same XCD's L2,
  // so adjacent 64B halves of 128B x/out lines are reused, not re-fetched.
  const int nwg = gridDim.x;
  int bid = blockIdx.x;
  if ((nwg & 7) == 0) bid = (bid & 7) * (nwg >> 3) + (bid >> 3);

  const int nb = bid * NT + nt;
  const int nbm = (nb < N) ? nb : (N - 1); // clamp loads; stores masked
  const int col = row * NT + nt;           // this thread's LDS column offset

  const float* Cp = ws + OFF_CP;
  const float* CtE = ws + OFF_CTE;
  const float* CtO = ws + OFF_CTO;

  // ---- Stage A1: DCT along tube of x[:, row, nb] (even/odd butterfly)
  {
    float h[28];
#pragma unroll
    for (int m = 0; m < 28; ++m) h[m] = x[(size_t)(m * 28 + row) * N + nbm];
    float u[14], v[14];
#pragma unroll
    for (int i = 0; i < 14; ++i) {
      u[i] = h[i] + h[27 - i];
      v[i] = h[i] - h[27 - i];
    }
#pragma unroll
    for (int k = 0; k < 28; ++k) {
      const float* uv = (k & 1) ? v : u;
      lds[k * ROWSTRIDE + col] = dot14(Cp + k * 16, uv);
    }
  }
  __syncthreads();

  // ---- layers 1..3
#pragma unroll 1
  for (int L = 0; L < 3; ++L) {
    const float* Wh = ws + (L == 0 ? OFF_WH1 : L == 1 ? OFF_WH2 : OFF_WH3);
    const float* bt = ws + (L == 0 ? OFF_BT1 : L == 1 ? OFF_BT2 : OFF_BT3) + row * 28;

    // Stage B: per-k matvec (row = k), in-place on own row
    {
      float h[28];
#pragma unroll
      for (int b = 0; b < 28; ++b) h[b] = lds[row * ROWSTRIDE + b * NT + nt];
      const float4* wb = reinterpret_cast<const float4*>(Wh + row * 784);
#pragma unroll 2
      for (int a = 0; a < 28; ++a)
        lds[row * ROWSTRIDE + a * NT + nt] = dotw4(wb + a * 7, h);
    }
    __syncthreads();

    // Stage C' (row = a, own column): IDCT butterfly + bias + ReLU ->
    // write u to rows 0..13, v to rows 14..27 (lets h die at ~34 live floats)
    {
      float h[28];
#pragma unroll
      for (int k = 0; k < 28; ++k) h[k] = lds[k * ROWSTRIDE + col];
#pragma unroll
      for (int i = 0; i < 14; ++i) {
        float E = dot14_str2<0>(CtE + i * 16, h); // even-k partial
        float O = dot14_str2<1>(CtO + i * 16, h); // odd-k partial
        float yi = fmaxf(E + O + bt[i], 0.f);      // y[i]
        float yr = fmaxf(E - O + bt[27 - i], 0.f); // y[27-i]
        lds[i * ROWSTRIDE + col] = yi + yr;        // u[i]
        lds[(14 + i) * ROWSTRIDE + col] = yi - yr; // v[i]
      }
    }
    // Stage A' (own column, no barrier needed): fwd-DCT from u/v
    {
      float u[14], v[14];
#pragma unroll
      for (int i = 0; i < 14; ++i) u[i] = lds[i * ROWSTRIDE + col];
#pragma unroll
      for (int i = 0; i < 14; ++i) v[i] = lds[(14 + i) * ROWSTRIDE + col];
#pragma unroll
      for (int k = 0; k < 28; ++k) {
        const float* uv = (k & 1) ? v : u;
        lds[k * ROWSTRIDE + col] = dot14(Cp + k * 16, uv);
      }
    }
    __syncthreads();
  }

  // ---- layer 4: Stage B4 (10 outputs per k-row)
  {
    float h[28];
#pragma unroll
    for (int b = 0; b < 28; ++b) h[b] = lds[row * ROWSTRIDE + b * NT + nt];
    const float4* wb4 = reinterpret_cast<const float4*>(ws + OFF_WH4 + row * 280);
#pragma unroll
    for (int a = 0; a < 10; ++a)
      lds[row * ROWSTRIDE + a * NT + nt] = dotw4(wb4 + a * 7, h);
  }
  __syncthreads();

  // ---- Stage C4: IDCT butterfly + bias, store (rows 0..9 active)
  if (row < 10 && nb < N) {
    float h[28];
#pragma unroll
    for (int k = 0; k < 28; ++k) h[k] = lds[k * ROWSTRIDE + col];
    const float* bt4 = ws + OFF_BT4 + row * 28;
#pragma unroll
    for (int i = 0; i < 14; ++i) {
      float E = dot14_str2<0>(CtE + i * 16, h);
      float O = dot14_str2<1>(CtO + i * 16, h);
      out[(size_t)(i * 10 + row) * N + nb] = E + O + bt4[i];
      out[(size_t)((27 - i) * 10 + row) * N + nb] = E - O + bt4[27 - i];
    }
  }
}

extern "C" void kernel_launch(void* const* d_in, const int* in_sizes, int n_in,
                              void* d_out, int out_size, void* d_ws, size_t ws_size,
                              hipStream_t stream) {
  const float* x = (const float*)d_in[0];
  const float* W1 = (const float*)d_in[1];
  const float* B1 = (const float*)d_in[2];
  const float* W2 = (const float*)d_in[3];
  const float* B2 = (const float*)d_in[4];
  const float* W3 = (const float*)d_in[5];
  const float* B3 = (const float*)d_in[6];
  const float* W4 = (const float*)d_in[7];
  const float* B4 = (const float*)d_in[8];
  float* ws = (float*)d_ws;

  const int N = in_sizes[0] / 784; // x is (28, 28, N)

  prep_kernel<<<128, 256, 0, stream>>>(W1, B1, W2, B2, W3, B3, W4, B4, ws);

  const int blocks = (N + NT - 1) / NT;
  tnn_kernel<<<blocks, 448, 0, stream>>>(x, ws, (float*)d_out, N);
}

// Round 10
// 1097.296 us; speedup vs baseline: 1.3116x; 1.1500x over previous
//
#include <hip/hip_runtime.h>
#include <math.h>

// ---------------------------------------------------------------------------
// tNN over DCT domain: 4 layers of  IDCT28 * blockdiag_k(What_k) * DCT28
// with bias+ReLU in spatial domain between layers.
//
//  R9 post-mortem: R9's counters were IDENTICAL to R5's (VGPR 64, WRITE
//  308MB, dur 1090us) -> the compiler store-to-load-forwarded the same-
//  thread LDS round-trip (no fence between C' write and A' read), re-fused
//  the stages, recreated the 56-float liveness, and spilled ~32 dwords/thread
//  (~235MB scratch writes; re-reads hit L2 so FETCH unaffected). Fix: a
//  zero-cost `asm volatile("" ::: "memory")` clobber between C' and A'
//  forces a real LDS reload -> peak liveness ~34 floats -> no spill at the
//  64-VGPR allocation of (448,4). Decisive signature: WRITE_SIZE -> ~78MB.
//
//  - prep_kernel: folds DCT into weights (What = C @ W), packed even/odd DCT
//    tables + transposed biases.
//  - tnn_kernel: 1 block = 16 columns, 448 threads = 28 (row) x 16 (col).
//    One 28x28x16 LDS tile, all stages in-place, 2 barriers/layer.
//    Stage B  (row=k):   h=own row; out[a] = What[k][a][.] . h     (float4 w)
//    Stage C' (col):     h=own col; E/O butterfly, +bias, ReLU, write u/v
//    [compiler memory fence]
//    Stage A' (col):     reload u/v, out[k] = C[k][.] . (k odd ? v : u)
//  - XCD-chunked bijective blockIdx swizzle for x/out L2 line locality.
// ---------------------------------------------------------------------------

#define NT 16
#define ROWSTRIDE (28 * NT + 8) // 456 words; %32==8 -> all accesses <=2-way (free)

// workspace layout (float offsets)
#define OFF_CP 0                    // [28][16] C[k][i] i<14 (pad 2)
#define OFF_CTE 448                 // [14][16] CtE[i][j] = C[2j][i]
#define OFF_CTO 672                 // [14][16] CtO[i][j] = C[2j+1][i]
#define OFF_WH1 896
#define OFF_WH2 (OFF_WH1 + 21952)
#define OFF_WH3 (OFF_WH2 + 21952)
#define OFF_WH4 (OFF_WH3 + 21952)
#define OFF_BT1 (OFF_WH4 + 7840)
#define OFF_BT2 (OFF_BT1 + 784)
#define OFF_BT3 (OFF_BT2 + 784)
#define OFF_BT4 (OFF_BT3 + 784)

__global__ void prep_kernel(const float* __restrict__ W1, const float* __restrict__ B1,
                            const float* __restrict__ W2, const float* __restrict__ B2,
                            const float* __restrict__ W3, const float* __restrict__ B3,
                            const float* __restrict__ W4, const float* __restrict__ B4,
                            float* __restrict__ ws) {
  __shared__ float Cs[784]; // per-block copy of the DCT matrix C[k][i]
  const int tid = threadIdx.x;
  for (int idx = tid; idx < 784; idx += blockDim.x) {
    int k = idx / 28, i = idx - k * 28;
    double ang = (3.14159265358979323846 * (double)((2 * i + 1) * k)) / 56.0;
    double sc = (k == 0) ? sqrt(1.0 / 28.0) : sqrt(2.0 / 28.0);
    Cs[idx] = (float)(cos(ang) * sc);
  }
  __syncthreads();

  if (blockIdx.x == 0) { // tiny tables: one block handles them
    for (int idx = tid; idx < 448; idx += blockDim.x) {
      int k = idx >> 4, i = idx & 15;
      ws[OFF_CP + idx] = (i < 14) ? Cs[k * 28 + i] : 0.f;
    }
    for (int idx = tid; idx < 224; idx += blockDim.x) {
      int i = idx >> 4, j = idx & 15;
      ws[OFF_CTE + idx] = (j < 14) ? Cs[(2 * j) * 28 + i] : 0.f;
      ws[OFF_CTO + idx] = (j < 14) ? Cs[(2 * j + 1) * 28 + i] : 0.f;
    }
    for (int idx = tid; idx < 784; idx += blockDim.x) {
      int a = idx / 28, l = idx - a * 28;
      ws[OFF_BT1 + idx] = B1[l * 28 + a];
      ws[OFF_BT2 + idx] = B2[l * 28 + a];
      ws[OFF_BT3 + idx] = B3[l * 28 + a];
    }
    for (int idx = tid; idx < 280; idx += blockDim.x) {
      int a = idx / 28, l = idx - a * 28;
      ws[OFF_BT4 + idx] = B4[l * 10 + a];
    }
  }

  const int gbase = blockIdx.x * blockDim.x + tid;
  const int gstride = gridDim.x * blockDim.x;

#define FOLD28(W, OFFW)                                                      \
  for (int idx = gbase; idx < 21952; idx += gstride) {                       \
    int k = idx / 784, r = idx - k * 784;                                    \
    const float* cr = Cs + k * 28;                                           \
    float s = 0.f;                                                           \
    _Pragma("unroll") for (int l = 0; l < 28; ++l)                           \
        s = fmaf(cr[l], W[l * 784 + r], s);                                  \
    ws[OFFW + idx] = s;                                                      \
  }
  FOLD28(W1, OFF_WH1)
  FOLD28(W2, OFF_WH2)
  FOLD28(W3, OFF_WH3)
#undef FOLD28
  for (int idx = gbase; idx < 7840; idx += gstride) { // layer 4: a-dim = 10
    int k = idx / 280, r = idx - k * 280;
    const float* cr = Cs + k * 28;
    float s = 0.f;
#pragma unroll
    for (int l = 0; l < 28; ++l) s = fmaf(cr[l], W4[l * 280 + r], s);
    ws[OFF_WH4 + idx] = s;
  }
}

// 14-term dot, contiguous h (uniform w base -> s_loads)
__device__ __forceinline__ float dot14(const float* __restrict__ w, const float* h) {
  float s0 = 0.f, s1 = 0.f, s2 = 0.f, s3 = 0.f;
#pragma unroll
  for (int j = 0; j < 12; j += 4) {
    s0 = fmaf(w[j + 0], h[j + 0], s0);
    s1 = fmaf(w[j + 1], h[j + 1], s1);
    s2 = fmaf(w[j + 2], h[j + 2], s2);
    s3 = fmaf(w[j + 3], h[j + 3], s3);
  }
  s0 = fmaf(w[12], h[12], s0);
  s1 = fmaf(w[13], h[13], s1);
  return (s0 + s1) + (s2 + s3);
}

// 14-term dot over h[2j+OFF] (even/odd halves of a 28-vector)
template <int OFF>
__device__ __forceinline__ float dot14_str2(const float* __restrict__ w, const float* h) {
  float s0 = 0.f, s1 = 0.f, s2 = 0.f, s3 = 0.f;
#pragma unroll
  for (int j = 0; j < 12; j += 4) {
    s0 = fmaf(w[j + 0], h[2 * j + OFF + 0], s0);
    s1 = fmaf(w[j + 1], h[2 * j + OFF + 2], s1);
    s2 = fmaf(w[j + 2], h[2 * j + OFF + 4], s2);
    s3 = fmaf(w[j + 3], h[2 * j + OFF + 6], s3);
  }
  s0 = fmaf(w[12], h[24 + OFF], s0);
  s1 = fmaf(w[13], h[26 + OFF], s1);
  return (s0 + s1) + (s2 + s3);
}

// 28-term dot via 7 float4 vector loads (lane-varying base)
__device__ __forceinline__ float dotw4(const float4* __restrict__ w4, const float* h) {
  float s0 = 0.f, s1 = 0.f, s2 = 0.f, s3 = 0.f;
#pragma unroll
  for (int q = 0; q < 7; ++q) {
    float4 w = w4[q];
    s0 = fmaf(w.x, h[4 * q + 0], s0);
    s1 = fmaf(w.y, h[4 * q + 1], s1);
    s2 = fmaf(w.z, h[4 * q + 2], s2);
    s3 = fmaf(w.w, h[4 * q + 3], s3);
  }
  return (s0 + s1) + (s2 + s3);
}

__global__ __launch_bounds__(448, 4) void tnn_kernel(const float* __restrict__ x,
                                                     const float* __restrict__ ws,
                                                     float* __restrict__ out, int N) {
  __shared__ float lds[28 * ROWSTRIDE];
  const int tid = threadIdx.x;
  const int nt = tid & (NT - 1);
  const int row = tid >> 4; // 0..27

  // XCD-chunked bijective swizzle: consecutive data-blocks -> same XCD's L2,
  // so adjacent 64B halves of 128B x/out lines are reused, not re-fetched.
  const int nwg = gridDim.x;
  int bid = blockIdx.x;
  if ((nwg & 7) == 0) bid = (bid & 7) * (nwg >> 3) + (bid >> 3);

  const int nb = bid * NT + nt;
  const int nbm = (nb < N) ? nb : (N - 1); // clamp loads; stores masked
  const int col = row * NT + nt;           // this thread's LDS column offset

  const float* Cp = ws + OFF_CP;
  const float* CtE = ws + OFF_CTE;
  const float* CtO = ws + OFF_CTO;

  // ---- Stage A1: DCT along tube of x[:, row, nb] (even/odd butterfly)
  {
    float h[28];
#pragma unroll
    for (int m = 0; m < 28; ++m) h[m] = x[(size_t)(m * 28 + row) * N + nbm];
    float u[14], v[14];
#pragma unroll
    for (int i = 0; i < 14; ++i) {
      u[i] = h[i] + h[27 - i];
      v[i] = h[i] - h[27 - i];
    }
#pragma unroll
    for (int k = 0; k < 28; ++k) {
      const float* uv = (k & 1) ? v : u;
      lds[k * ROWSTRIDE + col] = dot14(Cp + k * 16, uv);
    }
  }
  __syncthreads();

  // ---- layers 1..3
#pragma unroll 1
  for (int L = 0; L < 3; ++L) {
    const float* Wh = ws + (L == 0 ? OFF_WH1 : L == 1 ? OFF_WH2 : OFF_WH3);
    const float* bt = ws + (L == 0 ? OFF_BT1 : L == 1 ? OFF_BT2 : OFF_BT3) + row * 28;

    // Stage B: per-k matvec (row = k), in-place on own row
    {
      float h[28];
#pragma unroll
      for (int b = 0; b < 28; ++b) h[b] = lds[row * ROWSTRIDE + b * NT + nt];
      const float4* wb = reinterpret_cast<const float4*>(Wh + row * 784);
#pragma unroll 2
      for (int a = 0; a < 28; ++a)
        lds[row * ROWSTRIDE + a * NT + nt] = dotw4(wb + a * 7, h);
    }
    __syncthreads();

    // Stage C' (row = a, own column): IDCT butterfly + bias + ReLU ->
    // write u to rows 0..13, v to rows 14..27 (lets h die at ~34 live floats)
    {
      float h[28];
#pragma unroll
      for (int k = 0; k < 28; ++k) h[k] = lds[k * ROWSTRIDE + col];
#pragma unroll
      for (int i = 0; i < 14; ++i) {
        float E = dot14_str2<0>(CtE + i * 16, h); // even-k partial
        float O = dot14_str2<1>(CtO + i * 16, h); // odd-k partial
        float yi = fmaxf(E + O + bt[i], 0.f);      // y[i]
        float yr = fmaxf(E - O + bt[27 - i], 0.f); // y[27-i]
        lds[i * ROWSTRIDE + col] = yi + yr;        // u[i]
        lds[(14 + i) * ROWSTRIDE + col] = yi - yr; // v[i]
      }
    }
    // R9 fix: compiler memory fence. Without it, LLVM store-to-load-forwards
    // the u/v LDS round-trip (same thread, same address, no fence), re-fusing
    // C'+A' and recreating the 56-float liveness -> spill (R9 == R5 counters).
    // Zero runtime cost: not a barrier, just kills cross-fence forwarding.
    asm volatile("" ::: "memory");
    // Stage A' (own column, same-thread RAW -> no s_barrier needed): fwd-DCT
    {
      float u[14], v[14];
#pragma unroll
      for (int i = 0; i < 14; ++i) u[i] = lds[i * ROWSTRIDE + col];
#pragma unroll
      for (int i = 0; i < 14; ++i) v[i] = lds[(14 + i) * ROWSTRIDE + col];
#pragma unroll
      for (int k = 0; k < 28; ++k) {
        const float* uv = (k & 1) ? v : u;
        lds[k * ROWSTRIDE + col] = dot14(Cp + k * 16, uv);
      }
    }
    __syncthreads();
  }

  // ---- layer 4: Stage B4 (10 outputs per k-row)
  {
    float h[28];
#pragma unroll
    for (int b = 0; b < 28; ++b) h[b] = lds[row * ROWSTRIDE + b * NT + nt];
    const float4* wb4 = reinterpret_cast<const float4*>(ws + OFF_WH4 + row * 280);
#pragma unroll
    for (int a = 0; a < 10; ++a)
      lds[row * ROWSTRIDE + a * NT + nt] = dotw4(wb4 + a * 7, h);
  }
  __syncthreads();

  // ---- Stage C4: IDCT butterfly + bias, store (rows 0..9 active)
  if (row < 10 && nb < N) {
    float h[28];
#pragma unroll
    for (int k = 0; k < 28; ++k) h[k] = lds[k * ROWSTRIDE + col];
    const float* bt4 = ws + OFF_BT4 + row * 28;
#pragma unroll
    for (int i = 0; i < 14; ++i) {
      float E = dot14_str2<0>(CtE + i * 16, h);
      float O = dot14_str2<1>(CtO + i * 16, h);
      out[(size_t)(i * 10 + row) * N + nb] = E + O + bt4[i];
      out[(size_t)((27 - i) * 10 + row) * N + nb] = E - O + bt4[27 - i];
    }
  }
}

extern "C" void kernel_launch(void* const* d_in, const int* in_sizes, int n_in,
                              void* d_out, int out_size, void* d_ws, size_t ws_size,
                              hipStream_t stream) {
  const float* x = (const float*)d_in[0];
  const float* W1 = (const float*)d_in[1];
  const float* B1 = (const float*)d_in[2];
  const float* W2 = (const float*)d_in[3];
  const float* B2 = (const float*)d_in[4];
  const float* W3 = (const float*)d_in[5];
  const float* B3 = (const float*)d_in[6];
  const float* W4 = (const float*)d_in[7];
  const float* B4 = (const float*)d_in[8];
  float* ws = (float*)d_ws;

  const int N = in_sizes[0] / 784; // x is (28, 28, N)

  prep_kernel<<<128, 256, 0, stream>>>(W1, B1, W2, B2, W3, B3, W4, B4, ws);

  const int blocks = (N + NT - 1) / NT;
  tnn_kernel<<<blocks, 448, 0, stream>>>(x, ws, (float*)d_out, N);
}